// Round 10
// baseline (178446.814 us; speedup 1.0000x reference)
//
#include <hip/hip_runtime.h>
#include <hip/hip_bf16.h>

#define BB 64
#define TT 2048
#define HH 256
#define H4 1024
#define NC 10
#define WLS 36   // LDS-resident k2 slices: k2 in [64, 100)

typedef _Float16 half2v __attribute__((ext_vector_type(2)));

__device__ __forceinline__ float sigmoidf_(float x) {
    return 1.0f / (1.0f + expf(-x));
}

__device__ __forceinline__ float fdot2_(unsigned wu, half2v hv, float acc) {
#if __has_builtin(__builtin_amdgcn_fdot2)
    return __builtin_amdgcn_fdot2(__builtin_bit_cast(half2v, wu), hv, acc, false);
#else
    half2v w = __builtin_bit_cast(half2v, wu);
    return acc + (float)w[0] * (float)hv[0] + (float)w[1] * (float)hv[1];
#endif
}

// ---------------------------------------------------------------------------
// gx GEMM: gx[tc][b][n] = sum_k A[b][t0+tc][k] * W[n][k] + bias1[n] + bias2[n]
// ---------------------------------------------------------------------------
__global__ __launch_bounds__(256, 2)
void gemm_gx(const float* __restrict__ A, const float* __restrict__ W,
             const float* __restrict__ bias1, const float* __restrict__ bias2,
             float* __restrict__ gx, int t0, int Tstride)
{
    __shared__ float As[8][132];
    __shared__ float Bs[8][132];
    const int tid = threadIdx.x;
    const int m0 = blockIdx.y * 128, n0 = blockIdx.x * 128;
    const int tx = tid & 15, ty = tid >> 4;

    float acc[8][8];
#pragma unroll
    for (int i = 0; i < 8; i++)
#pragma unroll
        for (int j = 0; j < 8; j++) acc[i][j] = 0.f;

    const int mL = tid >> 1, half = tid & 1;
    const int gm = m0 + mL;
    const int b = gm & 63, tc = gm >> 6;
    const float* arow = A + ((size_t)b * Tstride + t0 + tc) * 256;
    const float* brow = W + (size_t)(n0 + mL) * 256;

    for (int k0 = 0; k0 < 256; k0 += 8) {
        float4 av = *(const float4*)(arow + k0 + half * 4);
        float4 bv = *(const float4*)(brow + k0 + half * 4);
        __syncthreads();
        As[half * 4 + 0][mL] = av.x; As[half * 4 + 1][mL] = av.y;
        As[half * 4 + 2][mL] = av.z; As[half * 4 + 3][mL] = av.w;
        Bs[half * 4 + 0][mL] = bv.x; Bs[half * 4 + 1][mL] = bv.y;
        Bs[half * 4 + 2][mL] = bv.z; Bs[half * 4 + 3][mL] = bv.w;
        __syncthreads();
#pragma unroll
        for (int k = 0; k < 8; k++) {
            float a[8], w[8];
            *(float4*)&a[0] = *(const float4*)&As[k][ty * 8];
            *(float4*)&a[4] = *(const float4*)&As[k][ty * 8 + 4];
            *(float4*)&w[0] = *(const float4*)&Bs[k][tx * 8];
            *(float4*)&w[4] = *(const float4*)&Bs[k][tx * 8 + 4];
#pragma unroll
            for (int i = 0; i < 8; i++)
#pragma unroll
                for (int j = 0; j < 8; j++) acc[i][j] += a[i] * w[j];
        }
    }
#pragma unroll
    for (int i = 0; i < 8; i++) {
        int m = m0 + ty * 8 + i;
        int bb = m & 63, tcc = m >> 6;
#pragma unroll
        for (int j = 0; j < 8; j++) {
            int n = n0 + tx * 8 + j;
            gx[((size_t)tcc * BB + bb) * H4 + n] = acc[i][j] + bias1[n] + bias2[n];
        }
    }
}

// ---------------------------------------------------------------------------
// Pack W_hh [1024][256] fp32 -> wpk[k2][tau] uint4; component q = half2 of
// ( W[q*256+tau][2*k2], W[q*256+tau][2*k2+1] ). grid 128, 256 threads.
// ---------------------------------------------------------------------------
__global__ void prep_w(const float* __restrict__ W, uint4* __restrict__ out)
{
    const int k2 = blockIdx.x, t = threadIdx.x;
    unsigned q4[4];
#pragma unroll
    for (int q = 0; q < 4; q++) {
        const float* wr = W + (size_t)(q * 256 + t) * 256 + 2 * k2;
        union { _Float16 h[2]; unsigned u; } cv;
        cv.h[0] = (_Float16)wr[0];
        cv.h[1] = (_Float16)wr[1];
        q4[q] = cv.u;
    }
    out[(size_t)k2 * 256 + t] = make_uint4(q4[0], q4[1], q4[2], q4[3]);
}

// ---------------------------------------------------------------------------
// Batch-parallel recurrence, zero cross-WG sync. One WG (256 thr) per batch.
// Thread tau owns unit tau (all 4 gate rows). Weight partition per thread:
//   k2 [0,64)   : 64 uint4 loaded via VOLATILE loads (exactly-once semantics:
//                 rematerialization illegal -> resident in VGPR or honest spill)
//   k2 [64,100) : LDS-resident, per-thread column wl[t*37+m] (imm <= 1648 B;
//                 hl at LDS offset 0 — no >64K static ds-offset anywhere)
//   k2 [100,128): streamed from L2 each step (112 KB/WG/step), in-loop loads
// ---------------------------------------------------------------------------
__global__ __launch_bounds__(256, 1)
void rec_batch_reg(const float* __restrict__ gx, const uint4* __restrict__ wpk,
                   float* __restrict__ hst, float* __restrict__ cst,
                   float* __restrict__ hseq, int TC, int writeH)
{
    // explicit LDS pool: hl first (low offsets), wl after
    __shared__ __align__(16) unsigned char pool[1088 + 256 * 37 * 16];
    _Float16* hlb = (_Float16*)pool;                 // [2][272] halves
    uint4*    wlq = (uint4*)(pool + 1088);           // [256][37] (t-major, +1 pad)

    const int b = blockIdx.x, t = threadIdx.x;

    // stage LDS slices k2 in [64,100): thread-private column, no race
#pragma unroll
    for (int m = 0; m < WLS; m++) wlq[t * 37 + m] = wpk[(64 + m) * 256 + t];

    // volatile-load resident half k2 in [0,64)
    uint4 w4[64];
    {
        const volatile unsigned* wv = (const volatile unsigned*)wpk;
#pragma unroll
        for (int k2 = 0; k2 < 64; k2++) {
            size_t base = ((size_t)k2 * 256 + t) * 4;
            w4[k2].x = wv[base + 0];
            w4[k2].y = wv[base + 1];
            w4[k2].z = wv[base + 2];
            w4[k2].w = wv[base + 3];
        }
    }

    float c = cst[b * HH + t];
    float lastH = hst[b * HH + t];
    hlb[t] = (_Float16)lastH;      // p=0 row at offset 0
    __syncthreads();

    int p = 0;
    for (int tc = 0; tc < TC; tc++) {
        const float* gp = gx + ((size_t)tc * BB + b) * H4 + t;
        float g0 = gp[0], g1 = gp[256], g2 = gp[512], g3 = gp[768];

        const uint4* hp4 = (const uint4*)(hlb + p * 272);
        float a0 = 0.f, a1 = 0.f, a2 = 0.f, a3 = 0.f;

        // ---- register-resident half: k2 in [0,64) ----
#pragma unroll
        for (int k8 = 0; k8 < 16; k8++) {
            uint4 hq = hp4[k8];
            half2v hv0 = __builtin_bit_cast(half2v, hq.x);
            half2v hv1 = __builtin_bit_cast(half2v, hq.y);
            half2v hv2 = __builtin_bit_cast(half2v, hq.z);
            half2v hv3 = __builtin_bit_cast(half2v, hq.w);
            a0 = fdot2_(w4[k8*4+0].x, hv0, a0);
            a1 = fdot2_(w4[k8*4+0].y, hv0, a1);
            a2 = fdot2_(w4[k8*4+0].z, hv0, a2);
            a3 = fdot2_(w4[k8*4+0].w, hv0, a3);
            a0 = fdot2_(w4[k8*4+1].x, hv1, a0);
            a1 = fdot2_(w4[k8*4+1].y, hv1, a1);
            a2 = fdot2_(w4[k8*4+1].z, hv1, a2);
            a3 = fdot2_(w4[k8*4+1].w, hv1, a3);
            a0 = fdot2_(w4[k8*4+2].x, hv2, a0);
            a1 = fdot2_(w4[k8*4+2].y, hv2, a1);
            a2 = fdot2_(w4[k8*4+2].z, hv2, a2);
            a3 = fdot2_(w4[k8*4+2].w, hv2, a3);
            a0 = fdot2_(w4[k8*4+3].x, hv3, a0);
            a1 = fdot2_(w4[k8*4+3].y, hv3, a1);
            a2 = fdot2_(w4[k8*4+3].z, hv3, a2);
            a3 = fdot2_(w4[k8*4+3].w, hv3, a3);
        }
        // ---- LDS-resident slices: k2 in [64,100), k8 16..24 ----
#pragma unroll
        for (int k8 = 16; k8 < 25; k8++) {
            uint4 hq = hp4[k8];
            half2v hv0 = __builtin_bit_cast(half2v, hq.x);
            half2v hv1 = __builtin_bit_cast(half2v, hq.y);
            half2v hv2 = __builtin_bit_cast(half2v, hq.z);
            half2v hv3 = __builtin_bit_cast(half2v, hq.w);
            uint4 q0 = wlq[t * 37 + 4 * (k8 - 16) + 0];
            uint4 q1 = wlq[t * 37 + 4 * (k8 - 16) + 1];
            uint4 q2 = wlq[t * 37 + 4 * (k8 - 16) + 2];
            uint4 q3 = wlq[t * 37 + 4 * (k8 - 16) + 3];
            a0 = fdot2_(q0.x, hv0, a0);
            a1 = fdot2_(q0.y, hv0, a1);
            a2 = fdot2_(q0.z, hv0, a2);
            a3 = fdot2_(q0.w, hv0, a3);
            a0 = fdot2_(q1.x, hv1, a0);
            a1 = fdot2_(q1.y, hv1, a1);
            a2 = fdot2_(q1.z, hv1, a2);
            a3 = fdot2_(q1.w, hv1, a3);
            a0 = fdot2_(q2.x, hv2, a0);
            a1 = fdot2_(q2.y, hv2, a1);
            a2 = fdot2_(q2.z, hv2, a2);
            a3 = fdot2_(q2.w, hv2, a3);
            a0 = fdot2_(q3.x, hv3, a0);
            a1 = fdot2_(q3.y, hv3, a1);
            a2 = fdot2_(q3.z, hv3, a2);
            a3 = fdot2_(q3.w, hv3, a3);
        }
        // ---- streamed slices: k2 in [100,128), k8 25..31 ----
#pragma unroll
        for (int k8 = 25; k8 < 32; k8++) {
            uint4 hq = hp4[k8];
            uint4 s0 = wpk[(k8*4+0) * 256 + t];
            uint4 s1 = wpk[(k8*4+1) * 256 + t];
            uint4 s2 = wpk[(k8*4+2) * 256 + t];
            uint4 s3 = wpk[(k8*4+3) * 256 + t];
            half2v hv0 = __builtin_bit_cast(half2v, hq.x);
            half2v hv1 = __builtin_bit_cast(half2v, hq.y);
            half2v hv2 = __builtin_bit_cast(half2v, hq.z);
            half2v hv3 = __builtin_bit_cast(half2v, hq.w);
            a0 = fdot2_(s0.x, hv0, a0);
            a1 = fdot2_(s0.y, hv0, a1);
            a2 = fdot2_(s0.z, hv0, a2);
            a3 = fdot2_(s0.w, hv0, a3);
            a0 = fdot2_(s1.x, hv1, a0);
            a1 = fdot2_(s1.y, hv1, a1);
            a2 = fdot2_(s1.z, hv1, a2);
            a3 = fdot2_(s1.w, hv1, a3);
            a0 = fdot2_(s2.x, hv2, a0);
            a1 = fdot2_(s2.y, hv2, a1);
            a2 = fdot2_(s2.z, hv2, a2);
            a3 = fdot2_(s2.w, hv2, a3);
            a0 = fdot2_(s3.x, hv3, a0);
            a1 = fdot2_(s3.y, hv3, a1);
            a2 = fdot2_(s3.z, hv3, a2);
            a3 = fdot2_(s3.w, hv3, a3);
        }

        float ig = sigmoidf_(a0 + g0), fg = sigmoidf_(a1 + g1);
        float gg = tanhf(a2 + g2),     og = sigmoidf_(a3 + g3);
        c = fg * c + ig * gg;
        float h = og * tanhf(c);
        lastH = h;
        if (writeH) hseq[((size_t)b * TC + tc) * HH + t] = h;
        hlb[(p ^ 1) * 272 + t] = (_Float16)h;
        __syncthreads();
        p ^= 1;
    }

    cst[b * HH + t] = c;
    hst[b * HH + t] = lastH;
}

// ---------------------------------------------------------------------------
__global__ void fc_kernel(const float* __restrict__ h2,
                          const float* __restrict__ Wfc,
                          const float* __restrict__ bfc,
                          float* __restrict__ out)
{
    __shared__ float hs[256];
    int b = blockIdx.x, tid = threadIdx.x;
    hs[tid] = h2[b * HH + tid];
    __syncthreads();
    if (tid < NC) {
        float s = bfc[tid];
        for (int k = 0; k < 256; k++) s += hs[k] * Wfc[tid * 256 + k];
        out[b * NC + tid] = s;
    }
}

// ---------------------------------------------------------------------------
extern "C" void kernel_launch(void* const* d_in, const int* in_sizes, int n_in,
                              void* d_out, int out_size, void* d_ws, size_t ws_size,
                              hipStream_t stream)
{
    const float* x    = (const float*)d_in[0];
    const float* Wih0 = (const float*)d_in[1];
    const float* Whh0 = (const float*)d_in[2];
    const float* bih0 = (const float*)d_in[3];
    const float* bhh0 = (const float*)d_in[4];
    const float* Wih1 = (const float*)d_in[5];
    const float* Whh1 = (const float*)d_in[6];
    const float* bih1 = (const float*)d_in[7];
    const float* bhh1 = (const float*)d_in[8];
    const float* Wfc  = (const float*)d_in[9];
    const float* bfc  = (const float*)d_in[10];

    float* ws = (float*)d_ws;

    int TC = TT;
    while (TC > 128) {
        size_t need = ((size_t)TC * BB * H4 + (size_t)TC * BB * HH +
                       2 * 131072 + 4 * (size_t)BB * HH + 1024) * 4;
        if (need <= ws_size) break;
        TC >>= 1;
    }

    float* gxb = ws;                                    // [TC][64][1024]
    float* h1c = gxb + (size_t)TC * BB * H4;            // [64][TC][256]
    uint4* wpk0 = (uint4*)(h1c + (size_t)TC * BB * HH); // [128][256] uint4
    uint4* wpk1 = wpk0 + 128 * 256;
    float* hs1 = (float*)(wpk1 + 128 * 256);            // 4 x [64][256] states
    float* cs1 = hs1 + BB * HH;
    float* hs2 = cs1 + BB * HH;
    float* cs2 = hs2 + BB * HH;

    hipMemsetAsync(hs1, 0, (size_t)4 * BB * HH * 4, stream);

    prep_w<<<128, 256, 0, stream>>>(Whh0, wpk0);
    prep_w<<<128, 256, 0, stream>>>(Whh1, wpk1);

    const int nchunk = TT / TC;
    for (int ch = 0; ch < nchunk; ch++) {
        int t0 = ch * TC;
        dim3 gg(8, TC * 64 / 128);
        gemm_gx<<<gg, 256, 0, stream>>>(x, Wih0, bih0, bhh0, gxb, t0, TT);
        rec_batch_reg<<<BB, 256, 0, stream>>>(gxb, wpk0, hs1, cs1, h1c, TC, 1);
        gemm_gx<<<gg, 256, 0, stream>>>(h1c, Wih1, bih1, bhh1, gxb, 0, TC);
        rec_batch_reg<<<BB, 256, 0, stream>>>(gxb, wpk1, hs2, cs2, nullptr, TC, 0);
    }

    fc_kernel<<<BB, 256, 0, stream>>>(hs2, Wfc, bfc, (float*)d_out);
}

// Round 11
// 15876.770 us; speedup vs baseline: 11.2395x; 11.2395x over previous
//
#include <hip/hip_runtime.h>
#include <hip/hip_bf16.h>

#define BB 64
#define TT 2048
#define HH 256
#define H4 1024
#define NC 10

typedef _Float16 half2v __attribute__((ext_vector_type(2)));

__device__ __forceinline__ float sigmoidf_(float x) {
    return 1.0f / (1.0f + expf(-x));
}

__device__ __forceinline__ float fdot2_(unsigned wu, half2v hv, float acc) {
#if __has_builtin(__builtin_amdgcn_fdot2)
    return __builtin_amdgcn_fdot2(__builtin_bit_cast(half2v, wu), hv, acc, false);
#else
    half2v w = __builtin_bit_cast(half2v, wu);
    return acc + (float)w[0] * (float)hv[0] + (float)w[1] * (float)hv[1];
#endif
}

// ---------------------------------------------------------------------------
// gx GEMM: gx[tc][b][n] = sum_k A[b][t0+tc][k] * W[n][k] + bias1[n] + bias2[n]
// ---------------------------------------------------------------------------
__global__ __launch_bounds__(256, 2)
void gemm_gx(const float* __restrict__ A, const float* __restrict__ W,
             const float* __restrict__ bias1, const float* __restrict__ bias2,
             float* __restrict__ gx, int t0, int Tstride)
{
    __shared__ float As[8][132];
    __shared__ float Bs[8][132];
    const int tid = threadIdx.x;
    const int m0 = blockIdx.y * 128, n0 = blockIdx.x * 128;
    const int tx = tid & 15, ty = tid >> 4;

    float acc[8][8];
#pragma unroll
    for (int i = 0; i < 8; i++)
#pragma unroll
        for (int j = 0; j < 8; j++) acc[i][j] = 0.f;

    const int mL = tid >> 1, half = tid & 1;
    const int gm = m0 + mL;
    const int b = gm & 63, tc = gm >> 6;
    const float* arow = A + ((size_t)b * Tstride + t0 + tc) * 256;
    const float* brow = W + (size_t)(n0 + mL) * 256;

    for (int k0 = 0; k0 < 256; k0 += 8) {
        float4 av = *(const float4*)(arow + k0 + half * 4);
        float4 bv = *(const float4*)(brow + k0 + half * 4);
        __syncthreads();
        As[half * 4 + 0][mL] = av.x; As[half * 4 + 1][mL] = av.y;
        As[half * 4 + 2][mL] = av.z; As[half * 4 + 3][mL] = av.w;
        Bs[half * 4 + 0][mL] = bv.x; Bs[half * 4 + 1][mL] = bv.y;
        Bs[half * 4 + 2][mL] = bv.z; Bs[half * 4 + 3][mL] = bv.w;
        __syncthreads();
#pragma unroll
        for (int k = 0; k < 8; k++) {
            float a[8], w[8];
            *(float4*)&a[0] = *(const float4*)&As[k][ty * 8];
            *(float4*)&a[4] = *(const float4*)&As[k][ty * 8 + 4];
            *(float4*)&w[0] = *(const float4*)&Bs[k][tx * 8];
            *(float4*)&w[4] = *(const float4*)&Bs[k][tx * 8 + 4];
#pragma unroll
            for (int i = 0; i < 8; i++)
#pragma unroll
                for (int j = 0; j < 8; j++) acc[i][j] += a[i] * w[j];
        }
    }
#pragma unroll
    for (int i = 0; i < 8; i++) {
        int m = m0 + ty * 8 + i;
        int bb = m & 63, tcc = m >> 6;
#pragma unroll
        for (int j = 0; j < 8; j++) {
            int n = n0 + tx * 8 + j;
            gx[((size_t)tcc * BB + bb) * H4 + n] = acc[i][j] + bias1[n] + bias2[n];
        }
    }
}

// ---------------------------------------------------------------------------
// Pack W_hh [1024][256] fp32 -> wpk[k2][tau] uint4; component q = half2 of
// ( W[q*256+tau][2*k2], W[q*256+tau][2*k2+1] ). grid 128, 256 threads.
// ---------------------------------------------------------------------------
__global__ void prep_w(const float* __restrict__ W, uint4* __restrict__ out)
{
    const int k2 = blockIdx.x, t = threadIdx.x;
    unsigned q4[4];
#pragma unroll
    for (int q = 0; q < 4; q++) {
        const float* wr = W + (size_t)(q * 256 + t) * 256 + 2 * k2;
        union { _Float16 h[2]; unsigned u; } cv;
        cv.h[0] = (_Float16)wr[0];
        cv.h[1] = (_Float16)wr[1];
        q4[q] = cv.u;
    }
    out[(size_t)k2 * 256 + t] = make_uint4(q4[0], q4[1], q4[2], q4[3]);
}

// ---------------------------------------------------------------------------
// Batch-parallel recurrence, zero cross-WG sync. One 512-thread WG per batch.
// Thread (tau = t&255, hh = t>>8) computes k2-half [hh*64, hh*64+64) of unit
// tau's 4 gate dots; hh=1 posts partials to LDS; hh=0 combines + gates.
// Per half (r = k2 - hh*64):
//   r [0,16) : VGPR-resident (16 quads = 64 VGPR, volatile loads - exactly
//              once, safe budget; R10 proved 64 quads spills at 256-VGPR cap)
//   r [16,32): LDS-resident (32 slices total = 128 KB, imm <= 61440)
//   r [32,64): streamed from L2 each step (262 KB/WG/step), prefetched
// h read as LDS wave-broadcast (all lanes same quad).
// ---------------------------------------------------------------------------
__global__ __launch_bounds__(512, 1)
void rec_batch2(const float* __restrict__ gx, const uint4* __restrict__ wpk,
                float* __restrict__ hst, float* __restrict__ cst,
                float* __restrict__ hseq, int TC, int writeH)
{
    // LDS pool: hl [2][272] halves (1088 B) | pre [256][4] floats (4 KB)
    //           | wl [32 slices][256 tau] uint4 (128 KB)
    __shared__ __align__(16) unsigned char pool[1088 + 4096 + 32 * 4096];
    _Float16* hlb = (_Float16*)pool;
    float*    pre = (float*)(pool + 1088);
    uint4*    wl  = (uint4*)(pool + 1088 + 4096);

    const int b = blockIdx.x, t = threadIdx.x;
    const int tau = t & 255, hh = t >> 8;

    // stage LDS slices: s in [0,16) -> k2 16+s (hh=0); s in [16,32) -> k2 64+s (hh=1)
#pragma unroll
    for (int m = 0; m < 16; m++) {
        int e = m * 512 + t;              // [0, 8192)
        int s = e >> 8, tp = e & 255;
        int k2g = (s < 16) ? (16 + s) : (64 + s);
        wl[e] = wpk[(size_t)k2g * 256 + tp];
    }

    // VGPR-resident quads: r in [0,16), k2g = hh*64 + r (volatile: load once)
    uint4 w4[16];
    {
        const volatile unsigned* wv = (const volatile unsigned*)wpk;
#pragma unroll
        for (int r = 0; r < 16; r++) {
            size_t base = ((size_t)(hh * 64 + r) * 256 + tau) * 4;
            w4[r].x = wv[base + 0];
            w4[r].y = wv[base + 1];
            w4[r].z = wv[base + 2];
            w4[r].w = wv[base + 3];
        }
    }

    const uint4* wbase = wl + hh * 4096 + tau;      // [rr*256] for LDS part
    const uint4* sbase = wpk + (size_t)(hh * 64 + 32) * 256 + tau;  // stream

    float c = 0.f, lastH = 0.f;
    if (hh == 0) {
        c = cst[b * HH + tau];
        lastH = hst[b * HH + tau];
        hlb[tau] = (_Float16)lastH;
    }
    __syncthreads();

    int p = 0;
    for (int tc = 0; tc < TC; tc++) {
        float g0 = 0.f, g1 = 0.f, g2 = 0.f, g3 = 0.f;
        if (hh == 0) {
            const float* gp = gx + ((size_t)tc * BB + b) * H4 + tau;
            g0 = gp[0]; g1 = gp[256]; g2 = gp[512]; g3 = gp[768];
        }

        // prefetch streamed quads r in [32,64)
        uint4 sq[32];
#pragma unroll
        for (int m = 0; m < 32; m++) sq[m] = sbase[m * 256];

        const uint4* hp4 = (const uint4*)(hlb + p * 272) + hh * 16;
        float a0 = 0.f, a1 = 0.f, a2 = 0.f, a3 = 0.f;

        // REG part: r = 4j+u, j in [0,4)
#pragma unroll
        for (int j = 0; j < 4; j++) {
            uint4 hq = hp4[j];
#pragma unroll
            for (int u = 0; u < 4; u++) {
                half2v hv = __builtin_bit_cast(half2v, hq[u]);
                uint4 w = w4[4 * j + u];
                a0 = fdot2_(w.x, hv, a0);
                a1 = fdot2_(w.y, hv, a1);
                a2 = fdot2_(w.z, hv, a2);
                a3 = fdot2_(w.w, hv, a3);
            }
        }
        // LDS part: r = 4j+u, j in [4,8); rr = r-16
#pragma unroll
        for (int j = 4; j < 8; j++) {
            uint4 hq = hp4[j];
#pragma unroll
            for (int u = 0; u < 4; u++) {
                uint4 w = wbase[(4 * (j - 4) + u) * 256];
                half2v hv = __builtin_bit_cast(half2v, hq[u]);
                a0 = fdot2_(w.x, hv, a0);
                a1 = fdot2_(w.y, hv, a1);
                a2 = fdot2_(w.z, hv, a2);
                a3 = fdot2_(w.w, hv, a3);
            }
        }
        // STREAM part: r = 4j+u, j in [8,16); m = r-32
#pragma unroll
        for (int j = 8; j < 16; j++) {
            uint4 hq = hp4[j];
#pragma unroll
            for (int u = 0; u < 4; u++) {
                half2v hv = __builtin_bit_cast(half2v, hq[u]);
                uint4 w = sq[4 * (j - 8) + u];
                a0 = fdot2_(w.x, hv, a0);
                a1 = fdot2_(w.y, hv, a1);
                a2 = fdot2_(w.z, hv, a2);
                a3 = fdot2_(w.w, hv, a3);
            }
        }

        if (hh == 1) {
            float4 v = make_float4(a0, a1, a2, a3);
            *(float4*)&pre[tau * 4] = v;
        }
        __syncthreads();

        if (hh == 0) {
            float4 po = *(const float4*)&pre[tau * 4];
            float ig = sigmoidf_(a0 + po.x + g0);
            float fg = sigmoidf_(a1 + po.y + g1);
            float gg = tanhf(a2 + po.z + g2);
            float og = sigmoidf_(a3 + po.w + g3);
            c = fg * c + ig * gg;
            float h = og * tanhf(c);
            lastH = h;
            if (writeH) hseq[((size_t)b * TC + tc) * HH + tau] = h;
            hlb[(p ^ 1) * 272 + tau] = (_Float16)h;
        }
        __syncthreads();
        p ^= 1;
    }

    if (hh == 0) {
        cst[b * HH + tau] = c;
        hst[b * HH + tau] = lastH;
    }
}

// ---------------------------------------------------------------------------
__global__ void fc_kernel(const float* __restrict__ h2,
                          const float* __restrict__ Wfc,
                          const float* __restrict__ bfc,
                          float* __restrict__ out)
{
    __shared__ float hs[256];
    int b = blockIdx.x, tid = threadIdx.x;
    hs[tid] = h2[b * HH + tid];
    __syncthreads();
    if (tid < NC) {
        float s = bfc[tid];
        for (int k = 0; k < 256; k++) s += hs[k] * Wfc[tid * 256 + k];
        out[b * NC + tid] = s;
    }
}

// ---------------------------------------------------------------------------
extern "C" void kernel_launch(void* const* d_in, const int* in_sizes, int n_in,
                              void* d_out, int out_size, void* d_ws, size_t ws_size,
                              hipStream_t stream)
{
    const float* x    = (const float*)d_in[0];
    const float* Wih0 = (const float*)d_in[1];
    const float* Whh0 = (const float*)d_in[2];
    const float* bih0 = (const float*)d_in[3];
    const float* bhh0 = (const float*)d_in[4];
    const float* Wih1 = (const float*)d_in[5];
    const float* Whh1 = (const float*)d_in[6];
    const float* bih1 = (const float*)d_in[7];
    const float* bhh1 = (const float*)d_in[8];
    const float* Wfc  = (const float*)d_in[9];
    const float* bfc  = (const float*)d_in[10];

    float* ws = (float*)d_ws;

    int TC = TT;
    while (TC > 128) {
        size_t need = ((size_t)TC * BB * H4 + (size_t)TC * BB * HH +
                       2 * 131072 + 4 * (size_t)BB * HH + 1024) * 4;
        if (need <= ws_size) break;
        TC >>= 1;
    }

    float* gxb = ws;                                    // [TC][64][1024]
    float* h1c = gxb + (size_t)TC * BB * H4;            // [64][TC][256]
    uint4* wpk0 = (uint4*)(h1c + (size_t)TC * BB * HH); // [128][256] uint4
    uint4* wpk1 = wpk0 + 128 * 256;
    float* hs1 = (float*)(wpk1 + 128 * 256);            // 4 x [64][256] states
    float* cs1 = hs1 + BB * HH;
    float* hs2 = cs1 + BB * HH;
    float* cs2 = hs2 + BB * HH;

    hipMemsetAsync(hs1, 0, (size_t)4 * BB * HH * 4, stream);

    prep_w<<<128, 256, 0, stream>>>(Whh0, wpk0);
    prep_w<<<128, 256, 0, stream>>>(Whh1, wpk1);

    const int nchunk = TT / TC;
    for (int ch = 0; ch < nchunk; ch++) {
        int t0 = ch * TC;
        dim3 gg(8, TC * 64 / 128);
        gemm_gx<<<gg, 256, 0, stream>>>(x, Wih0, bih0, bhh0, gxb, t0, TT);
        rec_batch2<<<BB, 512, 0, stream>>>(gxb, wpk0, hs1, cs1, h1c, TC, 1);
        gemm_gx<<<gg, 256, 0, stream>>>(h1c, Wih1, bih1, bhh1, gxb, 0, TC);
        rec_batch2<<<BB, 512, 0, stream>>>(gxb, wpk1, hs2, cs2, nullptr, TC, 0);
    }

    fc_kernel<<<BB, 256, 0, stream>>>(hs2, Wfc, bfc, (float*)d_out);
}

// Round 12
// 9958.314 us; speedup vs baseline: 17.9194x; 1.5943x over previous
//
#include <hip/hip_runtime.h>
#include <hip/hip_bf16.h>

#define BB 64
#define TT 2048
#define HH 256
#define H4 1024
#define NC 10

typedef _Float16 half2v __attribute__((ext_vector_type(2)));

__device__ __forceinline__ float sigmoidf_(float x) {
    return 1.0f / (1.0f + expf(-x));
}

__device__ __forceinline__ float fdot2_(unsigned wu, half2v hv, float acc) {
#if __has_builtin(__builtin_amdgcn_fdot2)
    return __builtin_amdgcn_fdot2(__builtin_bit_cast(half2v, wu), hv, acc, false);
#else
    half2v w = __builtin_bit_cast(half2v, wu);
    return acc + (float)w[0] * (float)hv[0] + (float)w[1] * (float)hv[1];
#endif
}

// ---------------------------------------------------------------------------
// gx GEMM: gx[tc][b][n] = sum_k A[b][t0+tc][k] * W[n][k] + bias1[n] + bias2[n]
// ---------------------------------------------------------------------------
__global__ __launch_bounds__(256, 2)
void gemm_gx(const float* __restrict__ A, const float* __restrict__ W,
             const float* __restrict__ bias1, const float* __restrict__ bias2,
             float* __restrict__ gx, int t0, int Tstride)
{
    __shared__ float As[8][132];
    __shared__ float Bs[8][132];
    const int tid = threadIdx.x;
    const int m0 = blockIdx.y * 128, n0 = blockIdx.x * 128;
    const int tx = tid & 15, ty = tid >> 4;

    float acc[8][8];
#pragma unroll
    for (int i = 0; i < 8; i++)
#pragma unroll
        for (int j = 0; j < 8; j++) acc[i][j] = 0.f;

    const int mL = tid >> 1, half = tid & 1;
    const int gm = m0 + mL;
    const int b = gm & 63, tc = gm >> 6;
    const float* arow = A + ((size_t)b * Tstride + t0 + tc) * 256;
    const float* brow = W + (size_t)(n0 + mL) * 256;

    for (int k0 = 0; k0 < 256; k0 += 8) {
        float4 av = *(const float4*)(arow + k0 + half * 4);
        float4 bv = *(const float4*)(brow + k0 + half * 4);
        __syncthreads();
        As[half * 4 + 0][mL] = av.x; As[half * 4 + 1][mL] = av.y;
        As[half * 4 + 2][mL] = av.z; As[half * 4 + 3][mL] = av.w;
        Bs[half * 4 + 0][mL] = bv.x; Bs[half * 4 + 1][mL] = bv.y;
        Bs[half * 4 + 2][mL] = bv.z; Bs[half * 4 + 3][mL] = bv.w;
        __syncthreads();
#pragma unroll
        for (int k = 0; k < 8; k++) {
            float a[8], w[8];
            *(float4*)&a[0] = *(const float4*)&As[k][ty * 8];
            *(float4*)&a[4] = *(const float4*)&As[k][ty * 8 + 4];
            *(float4*)&w[0] = *(const float4*)&Bs[k][tx * 8];
            *(float4*)&w[4] = *(const float4*)&Bs[k][tx * 8 + 4];
#pragma unroll
            for (int i = 0; i < 8; i++)
#pragma unroll
                for (int j = 0; j < 8; j++) acc[i][j] += a[i] * w[j];
        }
    }
#pragma unroll
    for (int i = 0; i < 8; i++) {
        int m = m0 + ty * 8 + i;
        int bb = m & 63, tcc = m >> 6;
#pragma unroll
        for (int j = 0; j < 8; j++) {
            int n = n0 + tx * 8 + j;
            gx[((size_t)tcc * BB + bb) * H4 + n] = acc[i][j] + bias1[n] + bias2[n];
        }
    }
}

// ---------------------------------------------------------------------------
// Pack W_hh [1024][256] fp32 -> wpk[k2][tau] uint4; component q = half2 of
// ( W[q*256+tau][2*k2], W[q*256+tau][2*k2+1] ). grid 128, 256 threads.
// ---------------------------------------------------------------------------
__global__ void prep_w(const float* __restrict__ W, uint4* __restrict__ out)
{
    const int k2 = blockIdx.x, t = threadIdx.x;
    unsigned q4[4];
#pragma unroll
    for (int q = 0; q < 4; q++) {
        const float* wr = W + (size_t)(q * 256 + t) * 256 + 2 * k2;
        union { _Float16 h[2]; unsigned u; } cv;
        cv.h[0] = (_Float16)wr[0];
        cv.h[1] = (_Float16)wr[1];
        q4[q] = cv.u;
    }
    out[(size_t)k2 * 256 + t] = make_uint4(q4[0], q4[1], q4[2], q4[3]);
}

// ---------------------------------------------------------------------------
// Batch-parallel recurrence, zero cross-WG sync. One 512-thread WG per batch.
// Thread (tau = t&255, hh = t>>8) computes k2-half [hh*64, hh*64+64) of unit
// tau's 4 gate dots; hh=1 posts partials to LDS; hh=0 combines + gates.
// Per half (r = k2 - hh*64):
//   r [0,40) : VGPR-resident, 40 quads = 160 VGPR, volatile loads (exactly-
//              once; total est ~215 VGPR < 256 cap; R10: 256 for weights
//              alone spills catastrophically, R11: 16 quads left 128 idle)
//   r [40,56): LDS-resident (32 slices total = 128 KB)
//   r [56,64): streamed from L2 each step (64 KB/WG/step), prefetched
// ---------------------------------------------------------------------------
__global__ __launch_bounds__(512, 1)
void rec_batch2(const float* __restrict__ gx, const uint4* __restrict__ wpk,
                float* __restrict__ hst, float* __restrict__ cst,
                float* __restrict__ hseq, int TC, int writeH)
{
    // LDS pool: hl [2][272] halves (1088 B) | pre [256][4] floats (4 KB)
    //           | wl [32 slices][256 tau] uint4 (128 KB)
    __shared__ __align__(16) unsigned char pool[1088 + 4096 + 32 * 4096];
    _Float16* hlb = (_Float16*)pool;
    float*    pre = (float*)(pool + 1088);
    uint4*    wl  = (uint4*)(pool + 1088 + 4096);

    const int b = blockIdx.x, t = threadIdx.x;
    const int tau = t & 255, hh = t >> 8;

    // stage LDS slices: s in [0,16) -> k2 = 40+s (hh=0 half, r 40..55)
    //                   s in [16,32) -> k2 = 88+s  (hh=1 half, r 40..55)
#pragma unroll
    for (int m = 0; m < 16; m++) {
        int e = m * 512 + t;              // [0, 8192)
        int s = e >> 8, tp = e & 255;
        int k2g = (s < 16) ? (40 + s) : (88 + s);
        wl[e] = wpk[(size_t)k2g * 256 + tp];
    }

    // VGPR-resident quads: r in [0,40), k2g = hh*64 + r (volatile: load once)
    uint4 w4[40];
    {
        const volatile unsigned* wv = (const volatile unsigned*)wpk;
#pragma unroll
        for (int r = 0; r < 40; r++) {
            size_t base = ((size_t)(hh * 64 + r) * 256 + tau) * 4;
            w4[r].x = wv[base + 0];
            w4[r].y = wv[base + 1];
            w4[r].z = wv[base + 2];
            w4[r].w = wv[base + 3];
        }
    }

    const uint4* wbase = wl + hh * 4096 + tau;                      // LDS part
    const uint4* sbase = wpk + (size_t)(hh * 64 + 56) * 256 + tau;  // stream

    float c = 0.f, lastH = 0.f;
    if (hh == 0) {
        c = cst[b * HH + tau];
        lastH = hst[b * HH + tau];
        hlb[tau] = (_Float16)lastH;
    }
    __syncthreads();

    int p = 0;
    for (int tc = 0; tc < TC; tc++) {
        float g0 = 0.f, g1 = 0.f, g2 = 0.f, g3 = 0.f;
        if (hh == 0) {
            const float* gp = gx + ((size_t)tc * BB + b) * H4 + tau;
            g0 = gp[0]; g1 = gp[256]; g2 = gp[512]; g3 = gp[768];
        }

        // prefetch streamed quads r in [56,64)
        uint4 sq[8];
#pragma unroll
        for (int m = 0; m < 8; m++) sq[m] = sbase[m * 256];

        const uint4* hp4 = (const uint4*)(hlb + p * 272) + hh * 16;
        float a0 = 0.f, a1 = 0.f, a2 = 0.f, a3 = 0.f;

        // REG part: r = 4j+u, j in [0,10)
#pragma unroll
        for (int j = 0; j < 10; j++) {
            uint4 hq = hp4[j];
#pragma unroll
            for (int u = 0; u < 4; u++) {
                half2v hv = __builtin_bit_cast(half2v, hq[u]);
                uint4 w = w4[4 * j + u];
                a0 = fdot2_(w.x, hv, a0);
                a1 = fdot2_(w.y, hv, a1);
                a2 = fdot2_(w.z, hv, a2);
                a3 = fdot2_(w.w, hv, a3);
            }
        }
        // LDS part: r = 4j+u, j in [10,14); slice = r-40
#pragma unroll
        for (int j = 10; j < 14; j++) {
            uint4 hq = hp4[j];
#pragma unroll
            for (int u = 0; u < 4; u++) {
                uint4 w = wbase[(4 * (j - 10) + u) * 256];
                half2v hv = __builtin_bit_cast(half2v, hq[u]);
                a0 = fdot2_(w.x, hv, a0);
                a1 = fdot2_(w.y, hv, a1);
                a2 = fdot2_(w.z, hv, a2);
                a3 = fdot2_(w.w, hv, a3);
            }
        }
        // STREAM part: r = 4j+u, j in [14,16); m = r-56
#pragma unroll
        for (int j = 14; j < 16; j++) {
            uint4 hq = hp4[j];
#pragma unroll
            for (int u = 0; u < 4; u++) {
                half2v hv = __builtin_bit_cast(half2v, hq[u]);
                uint4 w = sq[4 * (j - 14) + u];
                a0 = fdot2_(w.x, hv, a0);
                a1 = fdot2_(w.y, hv, a1);
                a2 = fdot2_(w.z, hv, a2);
                a3 = fdot2_(w.w, hv, a3);
            }
        }

        if (hh == 1) {
            float4 v = make_float4(a0, a1, a2, a3);
            *(float4*)&pre[tau * 4] = v;
        }
        __syncthreads();

        if (hh == 0) {
            float4 po = *(const float4*)&pre[tau * 4];
            float ig = sigmoidf_(a0 + po.x + g0);
            float fg = sigmoidf_(a1 + po.y + g1);
            float gg = tanhf(a2 + po.z + g2);
            float og = sigmoidf_(a3 + po.w + g3);
            c = fg * c + ig * gg;
            float h = og * tanhf(c);
            lastH = h;
            if (writeH) hseq[((size_t)b * TC + tc) * HH + tau] = h;
            hlb[(p ^ 1) * 272 + tau] = (_Float16)h;
        }
        __syncthreads();
        p ^= 1;
    }

    if (hh == 0) {
        cst[b * HH + tau] = c;
        hst[b * HH + tau] = lastH;
    }
}

// ---------------------------------------------------------------------------
__global__ void fc_kernel(const float* __restrict__ h2,
                          const float* __restrict__ Wfc,
                          const float* __restrict__ bfc,
                          float* __restrict__ out)
{
    __shared__ float hs[256];
    int b = blockIdx.x, tid = threadIdx.x;
    hs[tid] = h2[b * HH + tid];
    __syncthreads();
    if (tid < NC) {
        float s = bfc[tid];
        for (int k = 0; k < 256; k++) s += hs[k] * Wfc[tid * 256 + k];
        out[b * NC + tid] = s;
    }
}

// ---------------------------------------------------------------------------
extern "C" void kernel_launch(void* const* d_in, const int* in_sizes, int n_in,
                              void* d_out, int out_size, void* d_ws, size_t ws_size,
                              hipStream_t stream)
{
    const float* x    = (const float*)d_in[0];
    const float* Wih0 = (const float*)d_in[1];
    const float* Whh0 = (const float*)d_in[2];
    const float* bih0 = (const float*)d_in[3];
    const float* bhh0 = (const float*)d_in[4];
    const float* Wih1 = (const float*)d_in[5];
    const float* Whh1 = (const float*)d_in[6];
    const float* bih1 = (const float*)d_in[7];
    const float* bhh1 = (const float*)d_in[8];
    const float* Wfc  = (const float*)d_in[9];
    const float* bfc  = (const float*)d_in[10];

    float* ws = (float*)d_ws;

    int TC = TT;
    while (TC > 128) {
        size_t need = ((size_t)TC * BB * H4 + (size_t)TC * BB * HH +
                       2 * 131072 + 4 * (size_t)BB * HH + 1024) * 4;
        if (need <= ws_size) break;
        TC >>= 1;
    }

    float* gxb = ws;                                    // [TC][64][1024]
    float* h1c = gxb + (size_t)TC * BB * H4;            // [64][TC][256]
    uint4* wpk0 = (uint4*)(h1c + (size_t)TC * BB * HH); // [128][256] uint4
    uint4* wpk1 = wpk0 + 128 * 256;
    float* hs1 = (float*)(wpk1 + 128 * 256);            // 4 x [64][256] states
    float* cs1 = hs1 + BB * HH;
    float* hs2 = cs1 + BB * HH;
    float* cs2 = hs2 + BB * HH;

    hipMemsetAsync(hs1, 0, (size_t)4 * BB * HH * 4, stream);

    prep_w<<<128, 256, 0, stream>>>(Whh0, wpk0);
    prep_w<<<128, 256, 0, stream>>>(Whh1, wpk1);

    const int nchunk = TT / TC;
    for (int ch = 0; ch < nchunk; ch++) {
        int t0 = ch * TC;
        dim3 gg(8, TC * 64 / 128);
        gemm_gx<<<gg, 256, 0, stream>>>(x, Wih0, bih0, bhh0, gxb, t0, TT);
        rec_batch2<<<BB, 512, 0, stream>>>(gxb, wpk0, hs1, cs1, h1c, TC, 1);
        gemm_gx<<<gg, 256, 0, stream>>>(h1c, Wih1, bih1, bhh1, gxb, 0, TC);
        rec_batch2<<<BB, 512, 0, stream>>>(gxb, wpk1, hs2, cs2, nullptr, TC, 0);
    }

    fc_kernel<<<BB, 256, 0, stream>>>(hs2, Wfc, bfc, (float*)d_out);
}

// Round 13
// 8985.213 us; speedup vs baseline: 19.8601x; 1.1083x over previous
//
#include <hip/hip_runtime.h>
#include <hip/hip_bf16.h>

#define BB 64
#define TT 2048
#define HH 256
#define H4 1024
#define NC 10

typedef _Float16 half2v __attribute__((ext_vector_type(2)));
typedef _Float16 half8  __attribute__((ext_vector_type(8)));
typedef float    f32x4  __attribute__((ext_vector_type(4)));

__device__ __forceinline__ float sigmoidf_(float x) {
    return 1.0f / (1.0f + expf(-x));
}

__device__ __forceinline__ float fdot2_(unsigned wu, half2v hv, float acc) {
#if __has_builtin(__builtin_amdgcn_fdot2)
    return __builtin_amdgcn_fdot2(__builtin_bit_cast(half2v, wu), hv, acc, false);
#else
    half2v w = __builtin_bit_cast(half2v, wu);
    return acc + (float)w[0] * (float)hv[0] + (float)w[1] * (float)hv[1];
#endif
}

// ---------------------------------------------------------------------------
// fp32 -> fp16 vector convert (8 elems/thread)
// ---------------------------------------------------------------------------
__global__ void f32_to_f16(const float* __restrict__ in,
                           _Float16* __restrict__ out, int n8)
{
    int i = blockIdx.x * 256 + threadIdx.x;
    if (i >= n8) return;
    float4 v0 = ((const float4*)in)[2 * i];
    float4 v1 = ((const float4*)in)[2 * i + 1];
    half8 h;
    h[0] = (_Float16)v0.x; h[1] = (_Float16)v0.y;
    h[2] = (_Float16)v0.z; h[3] = (_Float16)v0.w;
    h[4] = (_Float16)v1.x; h[5] = (_Float16)v1.y;
    h[6] = (_Float16)v1.z; h[7] = (_Float16)v1.w;
    ((half8*)out)[i] = h;
}

// ---------------------------------------------------------------------------
// MFMA gx GEMM: gx[tc][b][n] = sum_k A16[b][t0+tc][k]*W16[n][k] + b1[n]+b2[n]
// Grid (4, TC): block = one tc (64 b-rows) x 256 n-cols. 4 waves; wave w owns
// rows w*16..w*16+16 x all 256 cols (16 mfma frags). A,W fp16 K-contiguous:
// frag = one half8/lane. mfma_f32_16x16x32_f16; D: col=lane&15, row=(l>>4)*4+r.
// ---------------------------------------------------------------------------
__global__ __launch_bounds__(256, 2)
void gemm_gx_mfma(const _Float16* __restrict__ A16, const _Float16* __restrict__ W16,
                  const float* __restrict__ bias1, const float* __restrict__ bias2,
                  float* __restrict__ gx, int t0, int Tstride)
{
    const int tid = threadIdx.x;
    const int w = tid >> 6, lane = tid & 63;
    const int n0 = blockIdx.x * 256;
    const int by = blockIdx.y;                    // tc index
    const int lrow = lane & 15, lkg = lane >> 4;

    const _Float16* arow = A16 + ((size_t)(w * 16 + lrow) * Tstride + t0 + by) * 256
                         + lkg * 8;
    const _Float16* wrow = W16 + (size_t)(n0 + lrow) * 256 + lkg * 8;

    f32x4 acc[16];
#pragma unroll
    for (int j = 0; j < 16; j++) acc[j] = (f32x4)(0.f);

#pragma unroll
    for (int k0 = 0; k0 < 256; k0 += 32) {
        half8 a = *(const half8*)(arow + k0);
#pragma unroll
        for (int j = 0; j < 16; j++) {
            half8 bf = *(const half8*)(wrow + (size_t)j * 16 * 256 + k0);
            acc[j] = __builtin_amdgcn_mfma_f32_16x16x32_f16(a, bf, acc[j], 0, 0, 0);
        }
    }

    const int bout = w * 16 + lkg * 4;            // output b base (+r)
#pragma unroll
    for (int j = 0; j < 16; j++) {
        int n = n0 + j * 16 + lrow;
        float bsum = bias1[n] + bias2[n];
#pragma unroll
        for (int r = 0; r < 4; r++) {
            gx[((size_t)by * BB + bout + r) * H4 + n] = acc[j][r] + bsum;
        }
    }
}

// ---------------------------------------------------------------------------
// Pack W_hh [1024][256] fp32 -> wpk[k2][tau] uint4; component q = half2 of
// ( W[q*256+tau][2*k2], W[q*256+tau][2*k2+1] ). grid 128, 256 threads.
// ---------------------------------------------------------------------------
__global__ void prep_w(const float* __restrict__ W, uint4* __restrict__ out)
{
    const int k2 = blockIdx.x, t = threadIdx.x;
    unsigned q4[4];
#pragma unroll
    for (int q = 0; q < 4; q++) {
        const float* wr = W + (size_t)(q * 256 + t) * 256 + 2 * k2;
        union { _Float16 h[2]; unsigned u; } cv;
        cv.h[0] = (_Float16)wr[0];
        cv.h[1] = (_Float16)wr[1];
        q4[q] = cv.u;
    }
    out[(size_t)k2 * 256 + t] = make_uint4(q4[0], q4[1], q4[2], q4[3]);
}

// ---------------------------------------------------------------------------
// Batch-parallel recurrence (unchanged from R12 except hseq is fp16).
// One 512-thread WG per batch; (tau,hh) k-split with LDS partial exchange.
//   r [0,40) : VGPR-resident (volatile), r [40,56): LDS, r [56,64): streamed.
// ---------------------------------------------------------------------------
__global__ __launch_bounds__(512, 1)
void rec_batch2(const float* __restrict__ gx, const uint4* __restrict__ wpk,
                float* __restrict__ hst, float* __restrict__ cst,
                _Float16* __restrict__ hseq, int TC, int writeH)
{
    __shared__ __align__(16) unsigned char pool[1088 + 4096 + 32 * 4096];
    _Float16* hlb = (_Float16*)pool;
    float*    pre = (float*)(pool + 1088);
    uint4*    wl  = (uint4*)(pool + 1088 + 4096);

    const int b = blockIdx.x, t = threadIdx.x;
    const int tau = t & 255, hh = t >> 8;

#pragma unroll
    for (int m = 0; m < 16; m++) {
        int e = m * 512 + t;
        int s = e >> 8, tp = e & 255;
        int k2g = (s < 16) ? (40 + s) : (88 + s);
        wl[e] = wpk[(size_t)k2g * 256 + tp];
    }

    uint4 w4[40];
    {
        const volatile unsigned* wv = (const volatile unsigned*)wpk;
#pragma unroll
        for (int r = 0; r < 40; r++) {
            size_t base = ((size_t)(hh * 64 + r) * 256 + tau) * 4;
            w4[r].x = wv[base + 0];
            w4[r].y = wv[base + 1];
            w4[r].z = wv[base + 2];
            w4[r].w = wv[base + 3];
        }
    }

    const uint4* wbase = wl + hh * 4096 + tau;
    const uint4* sbase = wpk + (size_t)(hh * 64 + 56) * 256 + tau;

    float c = 0.f, lastH = 0.f;
    if (hh == 0) {
        c = cst[b * HH + tau];
        lastH = hst[b * HH + tau];
        hlb[tau] = (_Float16)lastH;
    }
    __syncthreads();

    int p = 0;
    for (int tc = 0; tc < TC; tc++) {
        float g0 = 0.f, g1 = 0.f, g2 = 0.f, g3 = 0.f;
        if (hh == 0) {
            const float* gp = gx + ((size_t)tc * BB + b) * H4 + tau;
            g0 = gp[0]; g1 = gp[256]; g2 = gp[512]; g3 = gp[768];
        }

        uint4 sq[8];
#pragma unroll
        for (int m = 0; m < 8; m++) sq[m] = sbase[m * 256];

        const uint4* hp4 = (const uint4*)(hlb + p * 272) + hh * 16;
        float a0 = 0.f, a1 = 0.f, a2 = 0.f, a3 = 0.f;

#pragma unroll
        for (int j = 0; j < 10; j++) {
            uint4 hq = hp4[j];
#pragma unroll
            for (int u = 0; u < 4; u++) {
                half2v hv = __builtin_bit_cast(half2v, hq[u]);
                uint4 w = w4[4 * j + u];
                a0 = fdot2_(w.x, hv, a0);
                a1 = fdot2_(w.y, hv, a1);
                a2 = fdot2_(w.z, hv, a2);
                a3 = fdot2_(w.w, hv, a3);
            }
        }
#pragma unroll
        for (int j = 10; j < 14; j++) {
            uint4 hq = hp4[j];
#pragma unroll
            for (int u = 0; u < 4; u++) {
                uint4 w = wbase[(4 * (j - 10) + u) * 256];
                half2v hv = __builtin_bit_cast(half2v, hq[u]);
                a0 = fdot2_(w.x, hv, a0);
                a1 = fdot2_(w.y, hv, a1);
                a2 = fdot2_(w.z, hv, a2);
                a3 = fdot2_(w.w, hv, a3);
            }
        }
#pragma unroll
        for (int j = 14; j < 16; j++) {
            uint4 hq = hp4[j];
#pragma unroll
            for (int u = 0; u < 4; u++) {
                half2v hv = __builtin_bit_cast(half2v, hq[u]);
                uint4 w = sq[4 * (j - 14) + u];
                a0 = fdot2_(w.x, hv, a0);
                a1 = fdot2_(w.y, hv, a1);
                a2 = fdot2_(w.z, hv, a2);
                a3 = fdot2_(w.w, hv, a3);
            }
        }

        if (hh == 1) {
            float4 v = make_float4(a0, a1, a2, a3);
            *(float4*)&pre[tau * 4] = v;
        }
        __syncthreads();

        if (hh == 0) {
            float4 po = *(const float4*)&pre[tau * 4];
            float ig = sigmoidf_(a0 + po.x + g0);
            float fg = sigmoidf_(a1 + po.y + g1);
            float gg = tanhf(a2 + po.z + g2);
            float og = sigmoidf_(a3 + po.w + g3);
            c = fg * c + ig * gg;
            float h = og * tanhf(c);
            lastH = h;
            if (writeH) hseq[((size_t)b * TC + tc) * HH + tau] = (_Float16)h;
            hlb[(p ^ 1) * 272 + tau] = (_Float16)h;
        }
        __syncthreads();
        p ^= 1;
    }

    if (hh == 0) {
        cst[b * HH + tau] = c;
        hst[b * HH + tau] = lastH;
    }
}

// ---------------------------------------------------------------------------
__global__ void fc_kernel(const float* __restrict__ h2,
                          const float* __restrict__ Wfc,
                          const float* __restrict__ bfc,
                          float* __restrict__ out)
{
    __shared__ float hs[256];
    int b = blockIdx.x, tid = threadIdx.x;
    hs[tid] = h2[b * HH + tid];
    __syncthreads();
    if (tid < NC) {
        float s = bfc[tid];
        for (int k = 0; k < 256; k++) s += hs[k] * Wfc[tid * 256 + k];
        out[b * NC + tid] = s;
    }
}

// ---------------------------------------------------------------------------
extern "C" void kernel_launch(void* const* d_in, const int* in_sizes, int n_in,
                              void* d_out, int out_size, void* d_ws, size_t ws_size,
                              hipStream_t stream)
{
    const float* x    = (const float*)d_in[0];
    const float* Wih0 = (const float*)d_in[1];
    const float* Whh0 = (const float*)d_in[2];
    const float* bih0 = (const float*)d_in[3];
    const float* bhh0 = (const float*)d_in[4];
    const float* Wih1 = (const float*)d_in[5];
    const float* Whh1 = (const float*)d_in[6];
    const float* bih1 = (const float*)d_in[7];
    const float* bhh1 = (const float*)d_in[8];
    const float* Wfc  = (const float*)d_in[9];
    const float* bfc  = (const float*)d_in[10];

    // choose chunk size (bytes): gx fp32 + h1c fp16 + x16 fp16 + w16 x2 +
    // wpk x2 + states
    const size_t x16_b  = (size_t)BB * TT * HH * 2;
    const size_t w16_b  = (size_t)H4 * HH * 2;
    const size_t wpk_b  = (size_t)128 * 256 * 16;
    const size_t st_b   = (size_t)4 * BB * HH * 4;
    int TC = TT;
    while (TC > 128) {
        size_t need = (size_t)TC * BB * H4 * 4 + (size_t)TC * BB * HH * 2 +
                      x16_b + 2 * w16_b + 2 * wpk_b + st_b + 4096;
        if (need <= ws_size) break;
        TC >>= 1;
    }

    char* base = (char*)d_ws;
    float*     gxb  = (float*)base;
    char* pp = base + (size_t)TC * BB * H4 * 4;
    _Float16*  h1c  = (_Float16*)pp;      pp += (size_t)TC * BB * HH * 2;
    _Float16*  x16  = (_Float16*)pp;      pp += x16_b;
    _Float16*  w16a = (_Float16*)pp;      pp += w16_b;
    _Float16*  w16b = (_Float16*)pp;      pp += w16_b;
    uint4*     wpk0 = (uint4*)pp;         pp += wpk_b;
    uint4*     wpk1 = (uint4*)pp;         pp += wpk_b;
    float*     hs1  = (float*)pp;
    float*     cs1  = hs1 + BB * HH;
    float*     hs2  = cs1 + BB * HH;
    float*     cs2  = hs2 + BB * HH;

    hipMemsetAsync(hs1, 0, st_b, stream);

    prep_w<<<128, 256, 0, stream>>>(Whh0, wpk0);
    prep_w<<<128, 256, 0, stream>>>(Whh1, wpk1);
    f32_to_f16<<<(BB * TT * HH / 8 + 255) / 256, 256, 0, stream>>>(x, x16, BB * TT * HH / 8);
    f32_to_f16<<<(H4 * HH / 8 + 255) / 256, 256, 0, stream>>>(Wih0, w16a, H4 * HH / 8);
    f32_to_f16<<<(H4 * HH / 8 + 255) / 256, 256, 0, stream>>>(Wih1, w16b, H4 * HH / 8);

    const int nchunk = TT / TC;
    for (int ch = 0; ch < nchunk; ch++) {
        int t0 = ch * TC;
        dim3 gg(4, TC);
        gemm_gx_mfma<<<gg, 256, 0, stream>>>(x16, w16a, bih0, bhh0, gxb, t0, TT);
        rec_batch2<<<BB, 512, 0, stream>>>(gxb, wpk0, hs1, cs1, h1c, TC, 1);
        gemm_gx_mfma<<<gg, 256, 0, stream>>>(h1c, w16b, bih1, bhh1, gxb, 0, TC);
        rec_batch2<<<BB, 512, 0, stream>>>(gxb, wpk1, hs2, cs2, nullptr, TC, 0);
    }

    fc_kernel<<<BB, 256, 0, stream>>>(hs2, Wfc, bfc, (float*)d_out);
}

// Round 14
// 7881.040 us; speedup vs baseline: 22.6425x; 1.1401x over previous
//
#include <hip/hip_runtime.h>
#include <hip/hip_bf16.h>

#define BB 64
#define TT 2048
#define HH 256
#define H4 1024
#define NC 10

typedef _Float16 half2v __attribute__((ext_vector_type(2)));
typedef _Float16 half8  __attribute__((ext_vector_type(8)));
typedef float    f32x4  __attribute__((ext_vector_type(4)));

__device__ __forceinline__ float fsig_(float x) {
    return __fdividef(1.f, 1.f + __expf(-x));
}
__device__ __forceinline__ float ftanh_(float x) {
    return 1.f - __fdividef(2.f, __expf(2.f * x) + 1.f);
}

__device__ __forceinline__ float fdot2_(unsigned wu, half2v hv, float acc) {
#if __has_builtin(__builtin_amdgcn_fdot2)
    return __builtin_amdgcn_fdot2(__builtin_bit_cast(half2v, wu), hv, acc, false);
#else
    half2v w = __builtin_bit_cast(half2v, wu);
    return acc + (float)w[0] * (float)hv[0] + (float)w[1] * (float)hv[1];
#endif
}

// ---------------------------------------------------------------------------
// fp32 -> fp16 vector convert (8 elems/thread)
// ---------------------------------------------------------------------------
__global__ void f32_to_f16(const float* __restrict__ in,
                           _Float16* __restrict__ out, int n8)
{
    int i = blockIdx.x * 256 + threadIdx.x;
    if (i >= n8) return;
    float4 v0 = ((const float4*)in)[2 * i];
    float4 v1 = ((const float4*)in)[2 * i + 1];
    half8 h;
    h[0] = (_Float16)v0.x; h[1] = (_Float16)v0.y;
    h[2] = (_Float16)v0.z; h[3] = (_Float16)v0.w;
    h[4] = (_Float16)v1.x; h[5] = (_Float16)v1.y;
    h[6] = (_Float16)v1.z; h[7] = (_Float16)v1.w;
    ((half8*)out)[i] = h;
}

// ---------------------------------------------------------------------------
// MFMA gx GEMM -> fp16 output.
// gx16[tc][b][n] = (half)( sum_k A16[b][t0+tc][k]*W16[n][k] + b1[n]+b2[n] )
// Grid (4, TC): block = one tc x 256 n-cols; 4 waves x 16 frags.
// ---------------------------------------------------------------------------
__global__ __launch_bounds__(256, 2)
void gemm_gx_mfma(const _Float16* __restrict__ A16, const _Float16* __restrict__ W16,
                  const float* __restrict__ bias1, const float* __restrict__ bias2,
                  _Float16* __restrict__ gx, int t0, int Tstride)
{
    const int tid = threadIdx.x;
    const int w = tid >> 6, lane = tid & 63;
    const int n0 = blockIdx.x * 256;
    const int by = blockIdx.y;
    const int lrow = lane & 15, lkg = lane >> 4;

    const _Float16* arow = A16 + ((size_t)(w * 16 + lrow) * Tstride + t0 + by) * 256
                         + lkg * 8;
    const _Float16* wrow = W16 + (size_t)(n0 + lrow) * 256 + lkg * 8;

    f32x4 acc[16];
#pragma unroll
    for (int j = 0; j < 16; j++) acc[j] = (f32x4)(0.f);

#pragma unroll
    for (int k0 = 0; k0 < 256; k0 += 32) {
        half8 a = *(const half8*)(arow + k0);
#pragma unroll
        for (int j = 0; j < 16; j++) {
            half8 bf = *(const half8*)(wrow + (size_t)j * 16 * 256 + k0);
            acc[j] = __builtin_amdgcn_mfma_f32_16x16x32_f16(a, bf, acc[j], 0, 0, 0);
        }
    }

    const int bout = w * 16 + lkg * 4;
#pragma unroll
    for (int j = 0; j < 16; j++) {
        int n = n0 + j * 16 + lrow;
        float bsum = bias1[n] + bias2[n];
#pragma unroll
        for (int r = 0; r < 4; r++) {
            gx[((size_t)by * BB + bout + r) * H4 + n] = (_Float16)(acc[j][r] + bsum);
        }
    }
}

// ---------------------------------------------------------------------------
// Pack W_hh [1024][256] fp32 -> wpk[k2][tau] uint4 (fp16 pairs).
// ---------------------------------------------------------------------------
__global__ void prep_w(const float* __restrict__ W, uint4* __restrict__ out)
{
    const int k2 = blockIdx.x, t = threadIdx.x;
    unsigned q4[4];
#pragma unroll
    for (int q = 0; q < 4; q++) {
        const float* wr = W + (size_t)(q * 256 + t) * 256 + 2 * k2;
        union { _Float16 h[2]; unsigned u; } cv;
        cv.h[0] = (_Float16)wr[0];
        cv.h[1] = (_Float16)wr[1];
        q4[q] = cv.u;
    }
    out[(size_t)k2 * 256 + t] = make_uint4(q4[0], q4[1], q4[2], q4[3]);
}

// ---------------------------------------------------------------------------
// Batch-parallel recurrence, zero cross-WG sync, 512 thr/WG, 2-way k-split.
// Weight partition per half (r = k2 - hh*64):
//   r [0,48) : VGPR/AGPR-resident via volatile loads (192 dwords < 256 cap;
//              R13 evidence: allocator AGPR-backs these with no scratch)
//   r [48,64): LDS-resident (32 slices = 128 KB)
//   (no per-step weight streaming)
// gx fp16, loaded by hh=1 one step AHEAD (latency hidden under compute),
// folded into hh1's posted partial -> hh0's serial gate phase shrinks.
// ---------------------------------------------------------------------------
__global__ __launch_bounds__(512, 1)
void rec_batch3(const _Float16* __restrict__ gx, const uint4* __restrict__ wpk,
                float* __restrict__ hst, float* __restrict__ cst,
                _Float16* __restrict__ hseq, int TC, int writeH)
{
    __shared__ __align__(16) unsigned char pool[1088 + 4096 + 32 * 4096];
    _Float16* hlb = (_Float16*)pool;
    float*    pre = (float*)(pool + 1088);
    uint4*    wl  = (uint4*)(pool + 1088 + 4096);

    const int b = blockIdx.x, t = threadIdx.x;
    const int tau = t & 255, hh = t >> 8;

    // stage LDS slices: s in [0,16) -> k2 48+s (hh0 r48..63);
    //                   s in [16,32) -> k2 96+s (hh1 r48..63)
#pragma unroll
    for (int m = 0; m < 16; m++) {
        int e = m * 512 + t;
        int s = e >> 8, tp = e & 255;
        int k2g = (s < 16) ? (48 + s) : (96 + s);
        wl[e] = wpk[(size_t)k2g * 256 + tp];
    }

    // resident quads r in [0,48): volatile (exactly-once; AGPR-backed)
    uint4 w4[48];
    {
        const volatile unsigned* wv = (const volatile unsigned*)wpk;
#pragma unroll
        for (int r = 0; r < 48; r++) {
            size_t base = ((size_t)(hh * 64 + r) * 256 + tau) * 4;
            w4[r].x = wv[base + 0];
            w4[r].y = wv[base + 1];
            w4[r].z = wv[base + 2];
            w4[r].w = wv[base + 3];
        }
    }

    const uint4* wbase = wl + hh * 4096 + tau;

    float c = 0.f, lastH = 0.f;
    if (hh == 0) {
        c = cst[b * HH + tau];
        lastH = hst[b * HH + tau];
        hlb[tau] = (_Float16)lastH;
    }
    __syncthreads();

    // gx pipeline (hh==1 only): load step 0
    const _Float16* gbase = gx + (size_t)b * H4 + tau;
    float gc0 = 0.f, gc1 = 0.f, gc2 = 0.f, gc3 = 0.f;
    if (hh == 1) {
        const _Float16* gp = gbase;
        gc0 = (float)gp[0];   gc1 = (float)gp[256];
        gc2 = (float)gp[512]; gc3 = (float)gp[768];
    }

    int p = 0;
    for (int tc = 0; tc < TC; tc++) {
        // issue next-step gx loads early (hh1); latency hides under compute
        float gn0 = 0.f, gn1 = 0.f, gn2 = 0.f, gn3 = 0.f;
        if (hh == 1) {
            int tn = (tc + 1 < TC) ? tc + 1 : tc;
            const _Float16* gp = gbase + (size_t)tn * BB * H4;
            gn0 = (float)gp[0];   gn1 = (float)gp[256];
            gn2 = (float)gp[512]; gn3 = (float)gp[768];
        }

        const uint4* hp4 = (const uint4*)(hlb + p * 272) + hh * 16;
        float a0 = 0.f, a1 = 0.f, a2 = 0.f, a3 = 0.f;

        // REG part: r = 4j+u, j in [0,12)
#pragma unroll
        for (int j = 0; j < 12; j++) {
            uint4 hq = hp4[j];
#pragma unroll
            for (int u = 0; u < 4; u++) {
                half2v hv = __builtin_bit_cast(half2v, hq[u]);
                uint4 w = w4[4 * j + u];
                a0 = fdot2_(w.x, hv, a0);
                a1 = fdot2_(w.y, hv, a1);
                a2 = fdot2_(w.z, hv, a2);
                a3 = fdot2_(w.w, hv, a3);
            }
        }
        // LDS part: r = 4j+u, j in [12,16); slice = r-48
#pragma unroll
        for (int j = 12; j < 16; j++) {
            uint4 hq = hp4[j];
#pragma unroll
            for (int u = 0; u < 4; u++) {
                uint4 w = wbase[(4 * (j - 12) + u) * 256];
                half2v hv = __builtin_bit_cast(half2v, hq[u]);
                a0 = fdot2_(w.x, hv, a0);
                a1 = fdot2_(w.y, hv, a1);
                a2 = fdot2_(w.z, hv, a2);
                a3 = fdot2_(w.w, hv, a3);
            }
        }

        if (hh == 1) {
            // fold current-step gx into the posted partial
            float4 v = make_float4(a0 + gc0, a1 + gc1, a2 + gc2, a3 + gc3);
            *(float4*)&pre[tau * 4] = v;
        }
        __syncthreads();

        if (hh == 0) {
            float4 po = *(const float4*)&pre[tau * 4];
            float ig = fsig_(a0 + po.x);
            float fg = fsig_(a1 + po.y);
            float gg = ftanh_(a2 + po.z);
            float og = fsig_(a3 + po.w);
            c = fg * c + ig * gg;
            float h = og * ftanh_(c);
            lastH = h;
            if (writeH) hseq[((size_t)b * TC + tc) * HH + tau] = (_Float16)h;
            hlb[(p ^ 1) * 272 + tau] = (_Float16)h;
        }
        __syncthreads();
        p ^= 1;
        gc0 = gn0; gc1 = gn1; gc2 = gn2; gc3 = gn3;
    }

    if (hh == 0) {
        cst[b * HH + tau] = c;
        hst[b * HH + tau] = lastH;
    }
}

// ---------------------------------------------------------------------------
__global__ void fc_kernel(const float* __restrict__ h2,
                          const float* __restrict__ Wfc,
                          const float* __restrict__ bfc,
                          float* __restrict__ out)
{
    __shared__ float hs[256];
    int b = blockIdx.x, tid = threadIdx.x;
    hs[tid] = h2[b * HH + tid];
    __syncthreads();
    if (tid < NC) {
        float s = bfc[tid];
        for (int k = 0; k < 256; k++) s += hs[k] * Wfc[tid * 256 + k];
        out[b * NC + tid] = s;
    }
}

// ---------------------------------------------------------------------------
extern "C" void kernel_launch(void* const* d_in, const int* in_sizes, int n_in,
                              void* d_out, int out_size, void* d_ws, size_t ws_size,
                              hipStream_t stream)
{
    const float* x    = (const float*)d_in[0];
    const float* Wih0 = (const float*)d_in[1];
    const float* Whh0 = (const float*)d_in[2];
    const float* bih0 = (const float*)d_in[3];
    const float* bhh0 = (const float*)d_in[4];
    const float* Wih1 = (const float*)d_in[5];
    const float* Whh1 = (const float*)d_in[6];
    const float* bih1 = (const float*)d_in[7];
    const float* bhh1 = (const float*)d_in[8];
    const float* Wfc  = (const float*)d_in[9];
    const float* bfc  = (const float*)d_in[10];

    const size_t x16_b = (size_t)BB * TT * HH * 2;
    const size_t w16_b = (size_t)H4 * HH * 2;
    const size_t wpk_b = (size_t)128 * 256 * 16;
    const size_t st_b  = (size_t)4 * BB * HH * 4;
    int TC = TT;
    while (TC > 128) {
        size_t need = (size_t)TC * BB * H4 * 2 + (size_t)TC * BB * HH * 2 +
                      x16_b + 2 * w16_b + 2 * wpk_b + st_b + 4096;
        if (need <= ws_size) break;
        TC >>= 1;
    }

    char* base = (char*)d_ws;
    _Float16*  gxb  = (_Float16*)base;
    char* pp = base + (size_t)TC * BB * H4 * 2;
    _Float16*  h1c  = (_Float16*)pp;      pp += (size_t)TC * BB * HH * 2;
    _Float16*  x16  = (_Float16*)pp;      pp += x16_b;
    _Float16*  w16a = (_Float16*)pp;      pp += w16_b;
    _Float16*  w16b = (_Float16*)pp;      pp += w16_b;
    uint4*     wpk0 = (uint4*)pp;         pp += wpk_b;
    uint4*     wpk1 = (uint4*)pp;         pp += wpk_b;
    float*     hs1  = (float*)pp;
    float*     cs1  = hs1 + BB * HH;
    float*     hs2  = cs1 + BB * HH;
    float*     cs2  = hs2 + BB * HH;

    hipMemsetAsync(hs1, 0, st_b, stream);

    prep_w<<<128, 256, 0, stream>>>(Whh0, wpk0);
    prep_w<<<128, 256, 0, stream>>>(Whh1, wpk1);
    f32_to_f16<<<(BB * TT * HH / 8 + 255) / 256, 256, 0, stream>>>(x, x16, BB * TT * HH / 8);
    f32_to_f16<<<(H4 * HH / 8 + 255) / 256, 256, 0, stream>>>(Wih0, w16a, H4 * HH / 8);
    f32_to_f16<<<(H4 * HH / 8 + 255) / 256, 256, 0, stream>>>(Wih1, w16b, H4 * HH / 8);

    const int nchunk = TT / TC;
    for (int ch = 0; ch < nchunk; ch++) {
        int t0 = ch * TC;
        dim3 gg(4, TC);
        gemm_gx_mfma<<<gg, 256, 0, stream>>>(x16, w16a, bih0, bhh0, gxb, t0, TT);
        rec_batch3<<<BB, 512, 0, stream>>>(gxb, wpk0, hs1, cs1, h1c, TC, 1);
        gemm_gx_mfma<<<gg, 256, 0, stream>>>(h1c, w16b, bih1, bhh1, gxb, 0, TC);
        rec_batch3<<<BB, 512, 0, stream>>>(gxb, wpk1, hs2, cs2, nullptr, TC, 0);
    }

    fc_kernel<<<BB, 256, 0, stream>>>(hs2, Wfc, bfc, (float*)d_out);
}

// Round 15
// 4429.768 us; speedup vs baseline: 40.2836x; 1.7791x over previous
//
#include <hip/hip_runtime.h>
#include <hip/hip_bf16.h>

#define BB 64
#define TT 2048
#define HH 256
#define H4 1024
#define NC 10
#define CH 64            // steps per chunk
#define NCH (TT / CH)    // 32 chunks
#define NR 4             // gx ring slots

typedef _Float16 half2v __attribute__((ext_vector_type(2)));
typedef _Float16 half8  __attribute__((ext_vector_type(8)));
typedef float    f32x4  __attribute__((ext_vector_type(4)));

struct __align__(128) Line { unsigned v; unsigned pad[31]; };

__device__ __forceinline__ float fsig_(float x) {
    return __fdividef(1.f, 1.f + __expf(-x));
}
__device__ __forceinline__ float ftanh_(float x) {
    return 1.f - __fdividef(2.f, __expf(2.f * x) + 1.f);
}

__device__ __forceinline__ float fdot2_(unsigned wu, half2v hv, float acc) {
#if __has_builtin(__builtin_amdgcn_fdot2)
    return __builtin_amdgcn_fdot2(__builtin_bit_cast(half2v, wu), hv, acc, false);
#else
    half2v w = __builtin_bit_cast(half2v, wu);
    return acc + (float)w[0] * (float)hv[0] + (float)w[1] * (float)hv[1];
#endif
}

// wave-0 parallel poll of 64 flags; one acquire fence; releases whole WG.
__device__ __forceinline__ void wait_flags(Line* f, unsigned target, int tid) {
    if (tid < 64) {
        while (true) {
            unsigned v = __hip_atomic_load(&f[tid].v, __ATOMIC_RELAXED,
                                           __HIP_MEMORY_SCOPE_AGENT);
            if (__all(v >= target)) break;
            __builtin_amdgcn_s_sleep(2);
        }
        if (tid == 0)
            __builtin_amdgcn_fence(__ATOMIC_ACQUIRE, "agent");
    }
    __syncthreads();
}

// ---------------------------------------------------------------------------
__global__ void f32_to_f16(const float* __restrict__ in,
                           _Float16* __restrict__ out, int n8)
{
    int i = blockIdx.x * 256 + threadIdx.x;
    if (i >= n8) return;
    float4 v0 = ((const float4*)in)[2 * i];
    float4 v1 = ((const float4*)in)[2 * i + 1];
    half8 h;
    h[0] = (_Float16)v0.x; h[1] = (_Float16)v0.y;
    h[2] = (_Float16)v0.z; h[3] = (_Float16)v0.w;
    h[4] = (_Float16)v1.x; h[5] = (_Float16)v1.y;
    h[6] = (_Float16)v1.z; h[7] = (_Float16)v1.w;
    ((half8*)out)[i] = h;
}

// ---------------------------------------------------------------------------
__global__ void prep_w(const float* __restrict__ W, uint4* __restrict__ out)
{
    const int k2 = blockIdx.x, t = threadIdx.x;
    unsigned q4[4];
#pragma unroll
    for (int q = 0; q < 4; q++) {
        const float* wr = W + (size_t)(q * 256 + t) * 256 + 2 * k2;
        union { _Float16 h[2]; unsigned u; } cv;
        cv.h[0] = (_Float16)wr[0];
        cv.h[1] = (_Float16)wr[1];
        q4[q] = cv.u;
    }
    out[(size_t)k2 * 256 + t] = make_uint4(q4[0], q4[1], q4[2], q4[3]);
}

// ---------------------------------------------------------------------------
// 4-role pipelined persistent kernel, 256 WGs x 512 threads:
//  role0 wg[0,64)   : L1 recurrence, batch b=wg  (R14 engine)
//  role1 wg[64,128) : gemm1 MFMA worker (gx1 = x16*Wih0), ring backpressure
//  role2 wg[128,192): gemm2 MFMA worker (gx2 = h1c*Wih1), waits fL1
//  role3 wg[192,256): L2 recurrence, waits fG2
// Flags: chunk-grained point-to-point (release fence + relaxed store /
// relaxed poll + acquire fence), 32 handoffs per WG total.
// ---------------------------------------------------------------------------
__global__ __launch_bounds__(512, 1)
void lstm_pipe(const _Float16* __restrict__ x16,
               const _Float16* __restrict__ w16a, const _Float16* __restrict__ w16b,
               const float* __restrict__ bih0, const float* __restrict__ bhh0,
               const float* __restrict__ bih1, const float* __restrict__ bhh1,
               const uint4* __restrict__ wpk0, const uint4* __restrict__ wpk1,
               _Float16* __restrict__ gx1r, _Float16* __restrict__ gx2r,
               _Float16* __restrict__ h1c,
               float* __restrict__ hs1, float* __restrict__ cs1,
               float* __restrict__ hs2, float* __restrict__ cs2,
               Line* __restrict__ fG1, Line* __restrict__ fL1,
               Line* __restrict__ fG2, Line* __restrict__ fL2)
{
    __shared__ __align__(16) unsigned char pool[1088 + 4096 + 32 * 4096];
    _Float16* hlb = (_Float16*)pool;
    float*    pre = (float*)(pool + 1088);
    uint4*    wl  = (uint4*)(pool + 1088 + 4096);

    const int wg = blockIdx.x, tid = threadIdx.x;
    const int role = wg >> 6, sub = wg & 63;

    if (role == 1 || role == 2) {
        // ---------------- gemm worker ----------------
        const bool isG2 = (role == 2);
        const _Float16* A  = isG2 ? h1c  : x16;
        const _Float16* Wm = isG2 ? w16b : w16a;
        const float* b1 = isG2 ? bih1 : bih0;
        const float* b2 = isG2 ? bhh1 : bhh0;
        _Float16* outr  = isG2 ? gx2r : gx1r;
        Line* fOut      = isG2 ? fG2  : fG1;

        const int v = tid >> 6, lane = tid & 63;
        const int lrow = lane & 15, lkg = lane >> 4;
        const int rquad = v & 3, nqh = v >> 2;

        for (int c = 0; c < NCH; c++) {
            if (isG2) {
                wait_flags(fL1, (unsigned)(c + 1), tid);
                if (c >= NR) wait_flags(fL2, (unsigned)(c - (NR - 1)), tid);
            } else {
                if (c >= NR) wait_flags(fL1, (unsigned)(c - (NR - 1)), tid);
            }
            const int tc = c * CH + sub;
            const int slot = c % NR;
            const _Float16* arow =
                A + ((size_t)(rquad * 16 + lrow) * TT + tc) * 256 + lkg * 8;
#pragma unroll
            for (int pass = 0; pass < 2; pass++) {
                const int n0 = (nqh * 2 + pass) * 256;
                const _Float16* wrow = Wm + (size_t)(n0 + lrow) * 256 + lkg * 8;
                f32x4 acc[16];
#pragma unroll
                for (int j = 0; j < 16; j++) acc[j] = (f32x4)(0.f);
#pragma unroll
                for (int k0 = 0; k0 < 256; k0 += 32) {
                    half8 a = *(const half8*)(arow + k0);
#pragma unroll
                    for (int j = 0; j < 16; j++) {
                        half8 bf = *(const half8*)(wrow + (size_t)j * 16 * 256 + k0);
                        acc[j] = __builtin_amdgcn_mfma_f32_16x16x32_f16(a, bf, acc[j], 0, 0, 0);
                    }
                }
                const int bout = rquad * 16 + lkg * 4;
#pragma unroll
                for (int j = 0; j < 16; j++) {
                    int n = n0 + j * 16 + lrow;
                    float bsum = b1[n] + b2[n];
#pragma unroll
                    for (int r = 0; r < 4; r++) {
                        outr[((size_t)(slot * CH + sub) * BB + bout + r) * H4 + n] =
                            (_Float16)(acc[j][r] + bsum);
                    }
                }
            }
            __syncthreads();   // drain this WG's stores
            if (tid == 0) {
                __builtin_amdgcn_fence(__ATOMIC_RELEASE, "agent");
                __hip_atomic_store(&fOut[sub].v, (unsigned)(c + 1),
                                   __ATOMIC_RELAXED, __HIP_MEMORY_SCOPE_AGENT);
            }
        }
        return;
    }

    // ---------------- recurrence (role 0 = L1, role 3 = L2) ----------------
    const bool isL2 = (role == 3);
    const uint4* wpk = isL2 ? wpk1 : wpk0;
    const _Float16* gxr = isL2 ? gx2r : gx1r;
    float* hst = isL2 ? hs2 : hs1;
    float* cst = isL2 ? cs2 : cs1;
    Line* fIn  = isL2 ? fG2 : fG1;
    Line* fOut = isL2 ? fL2 : fL1;
    const int b = sub;
    const int tau = tid & 255, hh = tid >> 8;

    // stage LDS weight slices: s[0,16) -> k2 48+s (hh0), s[16,32) -> 96+s (hh1)
#pragma unroll
    for (int m = 0; m < 16; m++) {
        int e = m * 512 + tid;
        int s = e >> 8, tp = e & 255;
        int k2g = (s < 16) ? (48 + s) : (96 + s);
        wl[e] = wpk[(size_t)k2g * 256 + tp];
    }

    uint4 w4[48];
    {
        const volatile unsigned* wv = (const volatile unsigned*)wpk;
#pragma unroll
        for (int r = 0; r < 48; r++) {
            size_t base = ((size_t)(hh * 64 + r) * 256 + tau) * 4;
            w4[r].x = wv[base + 0];
            w4[r].y = wv[base + 1];
            w4[r].z = wv[base + 2];
            w4[r].w = wv[base + 3];
        }
    }

    const uint4* wbase = wl + hh * 4096 + tau;

    float c_ = 0.f, lastH = 0.f;
    if (hh == 0) {
        c_ = cst[b * HH + tau];
        lastH = hst[b * HH + tau];
        hlb[tau] = (_Float16)lastH;
    }
    __syncthreads();

    int p = 0;
    for (int ch = 0; ch < NCH; ch++) {
        wait_flags(fIn, (unsigned)(ch + 1), tid);
        const _Float16* gsl = gxr + (size_t)(ch % NR) * CH * BB * H4
                            + (size_t)b * H4 + tau;
        float gc0 = 0.f, gc1 = 0.f, gc2 = 0.f, gc3 = 0.f;
        if (hh == 1) {
            gc0 = (float)gsl[0];   gc1 = (float)gsl[256];
            gc2 = (float)gsl[512]; gc3 = (float)gsl[768];
        }

        for (int l = 0; l < CH; l++) {
            float gn0 = 0.f, gn1 = 0.f, gn2 = 0.f, gn3 = 0.f;
            if (hh == 1 && l < CH - 1) {
                const _Float16* gp = gsl + (size_t)(l + 1) * BB * H4;
                gn0 = (float)gp[0];   gn1 = (float)gp[256];
                gn2 = (float)gp[512]; gn3 = (float)gp[768];
            }

            const uint4* hp4 = (const uint4*)(hlb + p * 272) + hh * 16;
            float a0 = 0.f, a1 = 0.f, a2 = 0.f, a3 = 0.f;

#pragma unroll
            for (int j = 0; j < 12; j++) {
                uint4 hq = hp4[j];
#pragma unroll
                for (int u = 0; u < 4; u++) {
                    half2v hv = __builtin_bit_cast(half2v, hq[u]);
                    uint4 w = w4[4 * j + u];
                    a0 = fdot2_(w.x, hv, a0);
                    a1 = fdot2_(w.y, hv, a1);
                    a2 = fdot2_(w.z, hv, a2);
                    a3 = fdot2_(w.w, hv, a3);
                }
            }
#pragma unroll
            for (int j = 12; j < 16; j++) {
                uint4 hq = hp4[j];
#pragma unroll
                for (int u = 0; u < 4; u++) {
                    uint4 w = wbase[(4 * (j - 12) + u) * 256];
                    half2v hv = __builtin_bit_cast(half2v, hq[u]);
                    a0 = fdot2_(w.x, hv, a0);
                    a1 = fdot2_(w.y, hv, a1);
                    a2 = fdot2_(w.z, hv, a2);
                    a3 = fdot2_(w.w, hv, a3);
                }
            }

            if (hh == 1) {
                float4 vv = make_float4(a0 + gc0, a1 + gc1, a2 + gc2, a3 + gc3);
                *(float4*)&pre[tau * 4] = vv;
            }
            __syncthreads();

            if (hh == 0) {
                float4 po = *(const float4*)&pre[tau * 4];
                float ig = fsig_(a0 + po.x);
                float fg = fsig_(a1 + po.y);
                float gg = ftanh_(a2 + po.z);
                float og = fsig_(a3 + po.w);
                c_ = fg * c_ + ig * gg;
                float h = og * ftanh_(c_);
                lastH = h;
                if (!isL2) {
                    int tc = ch * CH + l;
                    h1c[((size_t)b * TT + tc) * HH + tau] = (_Float16)h;
                }
                hlb[(p ^ 1) * 272 + tau] = (_Float16)h;
            }
            __syncthreads();
            p ^= 1;
            gc0 = gn0; gc1 = gn1; gc2 = gn2; gc3 = gn3;
        }

        // publish chunk (h1c stores drained by the loop-end __syncthreads)
        if (tid == 0) {
            if (!isL2) __builtin_amdgcn_fence(__ATOMIC_RELEASE, "agent");
            __hip_atomic_store(&fOut[b].v, (unsigned)(ch + 1),
                               __ATOMIC_RELAXED, __HIP_MEMORY_SCOPE_AGENT);
        }
    }

    if (hh == 0) {
        cst[b * HH + tau] = c_;
        hst[b * HH + tau] = lastH;
    }
}

// ---------------------------------------------------------------------------
__global__ void fc_kernel(const float* __restrict__ h2,
                          const float* __restrict__ Wfc,
                          const float* __restrict__ bfc,
                          float* __restrict__ out)
{
    __shared__ float hs[256];
    int b = blockIdx.x, tid = threadIdx.x;
    hs[tid] = h2[b * HH + tid];
    __syncthreads();
    if (tid < NC) {
        float s = bfc[tid];
        for (int k = 0; k < 256; k++) s += hs[k] * Wfc[tid * 256 + k];
        out[b * NC + tid] = s;
    }
}

// ---------------------------------------------------------------------------
extern "C" void kernel_launch(void* const* d_in, const int* in_sizes, int n_in,
                              void* d_out, int out_size, void* d_ws, size_t ws_size,
                              hipStream_t stream)
{
    const float* x    = (const float*)d_in[0];
    const float* Wih0 = (const float*)d_in[1];
    const float* Whh0 = (const float*)d_in[2];
    const float* bih0 = (const float*)d_in[3];
    const float* bhh0 = (const float*)d_in[4];
    const float* Wih1 = (const float*)d_in[5];
    const float* Whh1 = (const float*)d_in[6];
    const float* bih1 = (const float*)d_in[7];
    const float* bhh1 = (const float*)d_in[8];
    const float* Wfc  = (const float*)d_in[9];
    const float* bfc  = (const float*)d_in[10];

    const size_t x16_b  = (size_t)BB * TT * HH * 2;      // 67.1 MB
    const size_t h1c_b  = x16_b;                          // 67.1 MB
    const size_t gxr_b  = (size_t)NR * CH * BB * H4 * 2;  // 33.6 MB
    const size_t w16_b  = (size_t)H4 * HH * 2;
    const size_t wpk_b  = (size_t)128 * 256 * 16;
    const size_t st_b   = (size_t)4 * BB * HH * 4;

    char* pp = (char*)d_ws;
    _Float16* x16  = (_Float16*)pp;  pp += x16_b;
    _Float16* h1c  = (_Float16*)pp;  pp += h1c_b;
    _Float16* gx1r = (_Float16*)pp;  pp += gxr_b;
    _Float16* gx2r = (_Float16*)pp;  pp += gxr_b;
    _Float16* w16a = (_Float16*)pp;  pp += w16_b;
    _Float16* w16b = (_Float16*)pp;  pp += w16_b;
    uint4*    wpk0 = (uint4*)pp;     pp += wpk_b;
    uint4*    wpk1 = (uint4*)pp;     pp += wpk_b;
    float*    hs1  = (float*)pp;
    float*    cs1  = hs1 + BB * HH;
    float*    hs2  = cs1 + BB * HH;
    float*    cs2  = hs2 + BB * HH;
    pp += st_b;
    Line* fG1 = (Line*)pp;
    Line* fL1 = fG1 + 64;
    Line* fG2 = fL1 + 64;
    Line* fL2 = fG2 + 64;

    // zero states + flags (contiguous)
    hipMemsetAsync(hs1, 0, st_b + 256 * sizeof(Line), stream);

    prep_w<<<128, 256, 0, stream>>>(Whh0, wpk0);
    prep_w<<<128, 256, 0, stream>>>(Whh1, wpk1);
    f32_to_f16<<<(BB * TT * HH / 8 + 255) / 256, 256, 0, stream>>>(x, x16, BB * TT * HH / 8);
    f32_to_f16<<<(H4 * HH / 8 + 255) / 256, 256, 0, stream>>>(Wih0, w16a, H4 * HH / 8);
    f32_to_f16<<<(H4 * HH / 8 + 255) / 256, 256, 0, stream>>>(Wih1, w16b, H4 * HH / 8);

    lstm_pipe<<<256, 512, 0, stream>>>(x16, w16a, w16b,
                                       bih0, bhh0, bih1, bhh1,
                                       wpk0, wpk1, gx1r, gx2r, h1c,
                                       hs1, cs1, hs2, cs2,
                                       fG1, fL1, fG2, fL2);

    fc_kernel<<<BB, 256, 0, stream>>>(hs2, Wfc, bfc, (float*)d_out);
}